// Round 8
// baseline (15310.371 us; speedup 1.0000x reference)
//
#include <hip/hip_runtime.h>
#include <hip/hip_bf16.h>

// ---------------------------------------------------------------------------
// 2-layer GRU, H=1200, B=64, T=512, I=30. Output = [h_last_l0, h_last_l1].
// R8: R7 point-to-point pipeline + PROPER release/acquire ordering.
//   role0 (75 blk): h0 step s   (W_hh0); ring-4 h0b; flag F0 = s+1
//   role1 (75 blk): gx1[t]      (W_ih1); reads h0b slot t+1; ring-2 gx; F1
//   role2 (75 blk): h1 step t   (W_hh1); ring-4 h1b; reads gx[t]; F2
// Producers: __syncthreads -> tid0 fence(release,agent) -> relaxed flag store.
// Consumers: relaxed poll -> fence(acquire,agent) -> data reads.
// Weights register/AGPR-resident (asm pin). State via agent atomics.
// ---------------------------------------------------------------------------

#define Hh 1200
#define HP 1280          // bf16 state row stride; cols >=1200 stay 0 forever
#define TT 512
#define II 30
#define KS_TOT 38        // 38*32 = 1216
#define KS_PW 5          // 8 waves x 5 = 40 k-units (last 2 read zero pad)
#define NTG 75
#define NBLK 225
#define NTHR 512

typedef __attribute__((ext_vector_type(8))) short short8;
typedef __attribute__((ext_vector_type(4))) float f32x4;

// workspace layout (bytes)
#define SZ_WF 17510400ull            // per matrix: 225*38*1024 elems * 2B
#define OFF_WHH0 0ull
#define OFF_WIH1 SZ_WF
#define OFF_WHH1 (2ull*SZ_WF)
#define SZ_HB 163840ull              // 64*1280 bf16
#define SZ_GX 921600ull              // 64*3600 fp32
#define OFF_H0B (3ull*SZ_WF)                 // ring 4
#define OFF_H1B (OFF_H0B + 4ull*SZ_HB)       // ring 4
#define OFF_GX  (OFF_H1B + 4ull*SZ_HB)       // ring 2
#define OFF_BAR (OFF_GX + 2ull*SZ_GX)        // flags: F0/F1/F2, 75 x 16B each
#define WS_NEEDED (OFF_BAR + 4096ull)        // ~55.69 MB

__device__ __forceinline__ unsigned short f2bf(float f){
  unsigned u = __float_as_uint(f);
  unsigned r = u + 0x7FFFu + ((u >> 16) & 1u);   // RNE
  return (unsigned short)(r >> 16);
}
__device__ __forceinline__ float bf2f(unsigned short s){
  return __uint_as_float(((unsigned)s) << 16);
}
__device__ __forceinline__ float sigmoid_f(float v){ return 1.f/(1.f + __expf(-v)); }
__device__ __forceinline__ float tanh_f(float v){ float e = __expf(2.f*v); return 1.f - 2.f/(e + 1.f); }
__device__ __forceinline__ unsigned long long pack2f(float a, float b){
  union { float f[2]; unsigned long long u; } v; v.f[0]=a; v.f[1]=b; return v.u;
}
__device__ __forceinline__ short8 aload16(const unsigned short* p){
  union { unsigned long long u[2]; short8 s; } v;
  const unsigned long long* q = (const unsigned long long*)p;
  v.u[0] = __hip_atomic_load(q,     __ATOMIC_RELAXED, __HIP_MEMORY_SCOPE_AGENT);
  v.u[1] = __hip_atomic_load(q + 1, __ATOMIC_RELAXED, __HIP_MEMORY_SCOPE_AGENT);
  return v.s;
}
__device__ __forceinline__ void aload2f(const float* p, float* f0, float* f1){
  union { unsigned long long u; float f[2]; } v;
  v.u = __hip_atomic_load((const unsigned long long*)p, __ATOMIC_RELAXED, __HIP_MEMORY_SCOPE_AGENT);
  *f0 = v.f[0]; *f1 = v.f[1];
}

#define POLLGE(addr, thr) \
  while (__hip_atomic_load((addr), __ATOMIC_RELAXED, __HIP_MEMORY_SCOPE_AGENT) < (thr)) \
    __builtin_amdgcn_s_sleep(1)
#define ACQ() __builtin_amdgcn_fence(__ATOMIC_ACQUIRE, "agent")

// Split W[3600][K<=1200] fp32 -> bf16 hi/lo in MFMA B-fragment order.
__global__ void prep_w(const float* __restrict__ W, unsigned short* __restrict__ Wf){
  int blk = blockIdx.x;
  int nt = blk / KS_TOT, ks = blk - nt*KS_TOT;
  int l = threadIdx.x;
  int n = nt*16 + (l & 15);
  int k0 = ks*32 + (l >> 4)*8;
  alignas(16) unsigned short hi[8];
  alignas(16) unsigned short lo[8];
  #pragma unroll
  for (int j = 0; j < 8; j++){
    int k = k0 + j;
    float w = (k < Hh) ? W[(size_t)n*Hh + k] : 0.f;
    unsigned short h16 = f2bf(w);
    hi[j] = h16;
    lo[j] = f2bf(w - bf2f(h16));
  }
  size_t cbase = ((size_t)(nt*KS_TOT + ks))*1024ull;
  *(short8*)(Wf + cbase + (size_t)l*8)        = *(const short8*)hi;
  *(short8*)(Wf + cbase + 512 + (size_t)l*8)  = *(const short8*)lo;
}

__global__ void init_state(char* __restrict__ ws){
  size_t i = (size_t)blockIdx.x*256 + threadIdx.x;
  size_t n_all = (WS_NEEDED - OFF_H0B)/16ull;   // rings + gx + flags
  if (i < n_all){
    f32x4 z = {0.f,0.f,0.f,0.f};
    ((f32x4*)(ws + OFF_H0B))[i] = z;
  }
}

#define COMPUTE_MFMA(AbPtr)                                                      \
  {                                                                              \
    _Pragma("unroll")                                                            \
    for (int g = 0; g < 3; g++)                                                  \
      _Pragma("unroll")                                                          \
      for (int m = 0; m < 4; m++) acc[g][m] = (f32x4){0.f,0.f,0.f,0.f};          \
    _Pragma("unroll")                                                            \
    for (int k = 0; k < KS_PW; k++){                                             \
      short8 a[4];                                                               \
      _Pragma("unroll")                                                          \
      for (int m = 0; m < 4; m++)                                                \
        a[m] = aload16(&(AbPtr)[(size_t)(m*16 + col)*HP + (ks0 + k)*32 + kg*8]); \
      _Pragma("unroll")                                                          \
      for (int g = 0; g < 3; g++)                                                \
        _Pragma("unroll")                                                        \
        for (int m = 0; m < 4; m++){                                             \
          acc[g][m] = __builtin_amdgcn_mfma_f32_16x16x32_bf16(a[m], wfr[g][k][0], acc[g][m], 0,0,0); \
          acc[g][m] = __builtin_amdgcn_mfma_f32_16x16x32_bf16(a[m], wfr[g][k][1], acc[g][m], 0,0,0); \
        }                                                                        \
    }                                                                            \
    _Pragma("unroll")                                                            \
    for (int g = 0; g < 3; g++)                                                  \
      _Pragma("unroll")                                                          \
      for (int m = 0; m < 4; m++)                                                \
        *(f32x4*)&part[g*4 + m][wv][lane*4] = acc[g][m];                         \
  }

#define REDUCE6()                                                                \
  {                                                                              \
    _Pragma("unroll")                                                            \
    for (int r = 0; r < 6; r++){                                                 \
      int o = r*NTHR + tid;                                                      \
      int tile = o >> 8, e = o & 255;                                            \
      red[tile][e] = part[tile][0][e] + part[tile][1][e] + part[tile][2][e]      \
                   + part[tile][3][e] + part[tile][4][e] + part[tile][5][e]      \
                   + part[tile][6][e] + part[tile][7][e];                        \
    }                                                                            \
  }

__global__ void __launch_bounds__(NTHR)
__attribute__((amdgpu_waves_per_eu(2)))
gru_persist(
    char* __restrict__ ws,
    const float* __restrict__ x,
    const float* __restrict__ Wih0,
    const float* __restrict__ bih0, const float* __restrict__ bhh0,
    const float* __restrict__ bih1, const float* __restrict__ bhh1,
    float* __restrict__ out)
{
  const int bid  = blockIdx.x;
  const int role = bid / NTG;
  const int nb   = bid - role*NTG;
  const int tid  = threadIdx.x;
  const int wv   = tid >> 6;
  const int lane = tid & 63;
  const int col  = lane & 15;
  const int kg   = lane >> 4;
  const int ks0  = wv * KS_PW;
  const int eb   = tid >> 3;           // epilogue batch 0..63
  const int ecp  = tid & 7;            // col pair 0..7
  const int c0   = ecp*2;
  const int gc0  = nb*16 + c0;

  __shared__ float part[12][8][256];   // 96 KB
  __shared__ float red[12][256];       // 12 KB
  __shared__ float xl[64][II];
  __shared__ float wl[48][II];
  __shared__ float hfl[64][16];

  int* F0 = (int*)(ws + OFF_BAR);      // 75 flags, 16B stride (int idx *4)
  int* F1 = F0 + 300;
  int* F2 = F0 + 600;

  for (int i = tid; i < 64*16; i += NTHR) ((float*)hfl)[i] = 0.f;

  // resident split weights: 3 gates x 5 ks x {hi,lo} = 30 short8 (120 regs)
  const short8* wt = (const short8*)(ws + ((role==0)?OFF_WHH0:(role==1)?OFF_WIH1:OFF_WHH1));
  short8 wfr[3][KS_PW][2];
  #pragma unroll
  for (int g = 0; g < 3; g++)
    #pragma unroll
    for (int k = 0; k < KS_PW; k++){
      int ks = ks0 + k;
      #pragma unroll
      for (int sp = 0; sp < 2; sp++){
        short8 v = {0,0,0,0,0,0,0,0};
        if (ks < KS_TOT)
          v = wt[((size_t)((g*NTG + nb)*KS_TOT + ks))*128 + sp*64 + lane];
        wfr[g][k][sp] = v;
        asm("" : "+v"(wfr[g][k][sp]));   // pin: no remat
      }
    }

  if (role == 0){
    for (int i = tid; i < 48*II; i += NTHR){
      int rl = i/II, c = i - rl*II;
      int g = rl >> 4, cl = rl & 15;
      wl[rl][c] = Wih0[(size_t)(g*Hh + nb*16 + cl)*II + c];
    }
  }

  float bIv[3][2] = {{0.f,0.f},{0.f,0.f},{0.f,0.f}};
  float bHv[3][2] = {{0.f,0.f},{0.f,0.f},{0.f,0.f}};
  if (role == 0){
    #pragma unroll
    for (int g = 0; g < 3; g++){
      bIv[g][0] = bih0[g*Hh + gc0]; bIv[g][1] = bih0[g*Hh + gc0 + 1];
      bHv[g][0] = bhh0[g*Hh + gc0]; bHv[g][1] = bhh0[g*Hh + gc0 + 1];
    }
  } else if (role == 1){
    #pragma unroll
    for (int g = 0; g < 3; g++){
      bIv[g][0] = bih1[g*Hh + gc0]; bIv[g][1] = bih1[g*Hh + gc0 + 1];
    }
  } else {
    #pragma unroll
    for (int g = 0; g < 3; g++){
      bHv[g][0] = bhh1[g*Hh + gc0]; bHv[g][1] = bhh1[g*Hh + gc0 + 1];
    }
  }

  const int pb = 10*wv + lane;         // per-wave producer index (lane<10)
  const bool pw = (lane < 10) && (pb < NTG);

  if (role == 0){
    // ---------------- layer0 recurrence ----------------
    for (int s = 0; s < TT; s++){
      for (int i = tid; i < 64*II; i += NTHR){
        int b = i/II, c = i - b*II;
        xl[b][c] = x[(size_t)b*(TT*II) + s*II + c];
      }
      if (s > 0){ if (pw) POLLGE(&F0[pb*4], s); ACQ(); }   // h0b slot s ready
      const unsigned short* Ab = (const unsigned short*)(ws + OFF_H0B + (size_t)(s&3)*SZ_HB);
      f32x4 acc[3][4];
      COMPUTE_MFMA(Ab);
      __syncthreads();
      REDUCE6();
      if (s >= 3 && tid < 75)                POLLGE(&F0[tid*4], s-2);        // WAR ring-4
      if (s >= 4 && tid >= 128 && tid < 203) POLLGE(&F1[(tid-128)*4], s-3);  // role1 consumed
      __syncthreads();
      {
        const int mt = eb >> 4, dr = eb & 15;
        const int e0 = ((dr>>2)<<6) | (c0<<2) | (dr&3);
        unsigned short* hbout = (unsigned short*)(ws + OFF_H0B + (size_t)((s+1)&3)*SZ_HB);
        float hq[2]; unsigned short hb2[2];
        #pragma unroll
        for (int j = 0; j < 2; j++){
          float g0 = bIv[0][j], g1 = bIv[1][j], g2 = bIv[2][j];
          #pragma unroll
          for (int i = 0; i < II; i++){
            float xv = xl[eb][i];
            g0 += wl[c0 + j][i]      * xv;
            g1 += wl[16 + c0 + j][i] * xv;
            g2 += wl[32 + c0 + j][i] * xv;
          }
          int e = e0 + j*4;
          float rr = sigmoid_f(red[mt][e]   + g0 + bHv[0][j]);
          float zz = sigmoid_f(red[4+mt][e] + g1 + bHv[1][j]);
          float nn = tanh_f(g2 + rr*(red[8+mt][e] + bHv[2][j]));
          float hold = hfl[eb][c0 + j];
          float hn = (1.f - zz)*nn + zz*hold;
          hfl[eb][c0 + j] = hn;
          hq[j] = hn; hb2[j] = f2bf(hn);
        }
        unsigned pk = (unsigned)hb2[0] | ((unsigned)hb2[1] << 16);
        __hip_atomic_store((unsigned*)&hbout[(size_t)eb*HP + gc0], pk,
                           __ATOMIC_RELAXED, __HIP_MEMORY_SCOPE_AGENT);
        if (s == TT-1){
          out[(size_t)eb*Hh + gc0]     = hq[0];
          out[(size_t)eb*Hh + gc0 + 1] = hq[1];
        }
      }
      __syncthreads();   // drains all waves' stores before flag
      if (tid == 0){
        __builtin_amdgcn_fence(__ATOMIC_RELEASE, "agent");
        __hip_atomic_store(&F0[nb*4], s+1, __ATOMIC_RELAXED, __HIP_MEMORY_SCOPE_AGENT);
      }
    }
  } else if (role == 1){
    // ---------------- layer1 input-side gx ----------------
    for (int t = 0; t < TT; t++){
      if (pw) POLLGE(&F0[pb*4], t+1);                  // out0[t] = slot t+1
      ACQ();
      const unsigned short* Ab = (const unsigned short*)(ws + OFF_H0B + (size_t)((t+1)&3)*SZ_HB);
      f32x4 acc[3][4];
      COMPUTE_MFMA(Ab);
      __syncthreads();
      REDUCE6();
      if (t >= 2 && tid == 0) POLLGE(&F2[nb*4], t-1);  // gx slot consumed
      __syncthreads();
      {
        const int mt = eb >> 4, dr = eb & 15;
        const int e0 = ((dr>>2)<<6) | (c0<<2) | (dr&3);
        float* gxo = (float*)(ws + OFF_GX + (size_t)(t&1)*SZ_GX);
        #pragma unroll
        for (int g = 0; g < 3; g++){
          float v0 = red[g*4+mt][e0]     + bIv[g][0];
          float v1 = red[g*4+mt][e0 + 4] + bIv[g][1];
          __hip_atomic_store((unsigned long long*)&gxo[(size_t)eb*3600 + g*Hh + gc0],
                             pack2f(v0, v1), __ATOMIC_RELAXED, __HIP_MEMORY_SCOPE_AGENT);
        }
      }
      __syncthreads();
      if (tid == 0){
        __builtin_amdgcn_fence(__ATOMIC_RELEASE, "agent");
        __hip_atomic_store(&F1[nb*4], t+1, __ATOMIC_RELAXED, __HIP_MEMORY_SCOPE_AGENT);
      }
    }
  } else {
    // ---------------- layer1 recurrence ----------------
    for (int t = 0; t < TT; t++){
      if (t > 0){ if (pw) POLLGE(&F2[pb*4], t); ACQ(); }   // h1b slot t ready
      const unsigned short* Ab = (const unsigned short*)(ws + OFF_H1B + (size_t)(t&3)*SZ_HB);
      f32x4 acc[3][4];
      COMPUTE_MFMA(Ab);
      __syncthreads();
      REDUCE6();
      if (tid == 0) POLLGE(&F1[nb*4], t+1);            // gx[t] ready
      if (t >= 3 && tid >= 64 && tid < 139) POLLGE(&F2[(tid-64)*4], t-2); // WAR ring-4
      ACQ();
      __syncthreads();
      {
        const int mt = eb >> 4, dr = eb & 15;
        const int e0 = ((dr>>2)<<6) | (c0<<2) | (dr&3);
        const float* gxi = (const float*)(ws + OFF_GX + (size_t)(t&1)*SZ_GX);
        unsigned short* hbout = (unsigned short*)(ws + OFF_H1B + (size_t)((t+1)&3)*SZ_HB);
        float gxv[3][2];
        #pragma unroll
        for (int g = 0; g < 3; g++)
          aload2f(&gxi[(size_t)eb*3600 + g*Hh + gc0], &gxv[g][0], &gxv[g][1]);
        float hq[2]; unsigned short hb2[2];
        #pragma unroll
        for (int j = 0; j < 2; j++){
          int e = e0 + j*4;
          float rr = sigmoid_f(red[mt][e]   + gxv[0][j] + bHv[0][j]);
          float zz = sigmoid_f(red[4+mt][e] + gxv[1][j] + bHv[1][j]);
          float nn = tanh_f(gxv[2][j] + rr*(red[8+mt][e] + bHv[2][j]));
          float hold = hfl[eb][c0 + j];
          float hn = (1.f - zz)*nn + zz*hold;
          hfl[eb][c0 + j] = hn;
          hq[j] = hn; hb2[j] = f2bf(hn);
        }
        unsigned pk = (unsigned)hb2[0] | ((unsigned)hb2[1] << 16);
        __hip_atomic_store((unsigned*)&hbout[(size_t)eb*HP + gc0], pk,
                           __ATOMIC_RELAXED, __HIP_MEMORY_SCOPE_AGENT);
        if (t == TT-1){
          out[76800 + (size_t)eb*Hh + gc0]     = hq[0];
          out[76800 + (size_t)eb*Hh + gc0 + 1] = hq[1];
        }
      }
      __syncthreads();
      if (tid == 0){
        __builtin_amdgcn_fence(__ATOMIC_RELEASE, "agent");
        __hip_atomic_store(&F2[nb*4], t+1, __ATOMIC_RELAXED, __HIP_MEMORY_SCOPE_AGENT);
      }
    }
  }
}

extern "C" void kernel_launch(void* const* d_in, const int* in_sizes, int n_in,
                              void* d_out, int out_size, void* d_ws, size_t ws_size,
                              hipStream_t stream)
{
  const float* x    = (const float*)d_in[0];
  const float* Wih0 = (const float*)d_in[1];
  const float* Whh0 = (const float*)d_in[2];
  const float* bih0 = (const float*)d_in[3];
  const float* bhh0 = (const float*)d_in[4];
  const float* Wih1 = (const float*)d_in[5];
  const float* Whh1 = (const float*)d_in[6];
  const float* bih1 = (const float*)d_in[7];
  const float* bhh1 = (const float*)d_in[8];
  char* ws = (char*)d_ws;
  if (ws_size < WS_NEEDED) return;   // ~55.7 MB scratch

  dim3 pgrid(NBLK*KS_TOT);
  prep_w<<<pgrid, 64, 0, stream>>>(Whh0, (unsigned short*)(ws + OFF_WHH0));
  prep_w<<<pgrid, 64, 0, stream>>>(Wih1, (unsigned short*)(ws + OFF_WIH1));
  prep_w<<<pgrid, 64, 0, stream>>>(Whh1, (unsigned short*)(ws + OFF_WHH1));
  init_state<<<772, 256, 0, stream>>>(ws);

  gru_persist<<<NBLK, NTHR, 0, stream>>>(ws, x, Wih0, bih0, bhh0, bih1, bhh1,
                                         (float*)d_out);
}